// Round 6
// baseline (1649.485 us; speedup 1.0000x reference)
//
#include <hip/hip_runtime.h>

// Centroids: argmin_c ||latent[r] - coords[c]||^2, 131072 rows x 2048 coords, D=128.
//
// prep_coords: coords -> bf16 hi/lo "B images", XOR-swizzled granules (contiguous
//   LDS copy AND conflict-free frag ds_read_b128), + c2, + counter=0.
// centroid_fast: A fragments converted f32->bf16x2 IN-REGISTER from latent
//   (fragment layout == 8 consecutive floats per lane -> direct load, no LDS, no
//   prep pass). Per 64-coord chunk: stage 32 KB B, ds_read frags, bf16x2 3-pass
//   MFMA (Ahh+Ahl+Alh), fused argmin epilogue (best/best2/idx), butterfly +
//   LDS exchange merge. LDS ~34 KB, __launch_bounds__(256,3) -> 3 blocks/CU
//   (R5 lesson: 1 wave/SIMD left 58% of cycles in naked stalls).
// refine_fp64: rows with gap < MARGIN recomputed exactly in fp64 (~0.5%).
//
// ws layout (bytes): 0 c2 | 8192 counter | 16384 worklist(128KB) |
//                    262144 Bh (512KB) | 786432 Bl (512KB) | end 1310720

constexpr int D = 128;
constexpr int C = 2048;
constexpr int NCH = 64;            // coords per chunk
constexpr int NCHUNKS = C / NCH;   // 32
constexpr float MARGIN = 0.02f;    // bf16x2 worst-case score err ~5e-3 -> 4x headroom
constexpr int WL_CAP = 32768;

constexpr size_t WS_CNT = 8192;
constexpr size_t WS_WL  = 16384;
constexpr size_t WS_BH  = 262144;
constexpr size_t WS_BL  = 786432;

typedef __attribute__((ext_vector_type(8))) short short8;
typedef __attribute__((ext_vector_type(4))) float f32x4;

__device__ inline unsigned short bf16_rne(float x) {
    unsigned u = __float_as_uint(x);
    u += 0x7FFFu + ((u >> 16) & 1u);
    return (unsigned short)(u >> 16);
}
__device__ inline float bf16_to_f(unsigned short h) {
    return __uint_as_float(((unsigned)h) << 16);
}
__device__ inline void split8(const float* v, short8* hi, short8* lo) {
#pragma unroll
    for (int j = 0; j < 8; ++j) {
        unsigned short h = bf16_rne(v[j]);
        (*hi)[j] = (short)h;
        (*lo)[j] = (short)bf16_rne(v[j] - bf16_to_f(h));
    }
}

// ---------------- prep: B images + c2 ----------------
// 32768 threads: thread t -> coord c = t>>4, k-granule k8 = t&15.
// Image: chunk ch = c>>6, nl = c&63; granule g = nl*16 + (k8 ^ (nl&15)).
__global__ void prep_coords(const float* __restrict__ coords,
                            unsigned short* __restrict__ Bh,
                            unsigned short* __restrict__ Bl,
                            float* __restrict__ c2, int* __restrict__ counter) {
    int t = blockIdx.x * blockDim.x + threadIdx.x;
    if (t == 0) *counter = 0;
    if (t >= C * 16) return;
    int c  = t >> 4;
    int k8 = t & 15;
    float v[8];
    *(float4*)(v)     = *(const float4*)(coords + (size_t)c * D + k8 * 8);
    *(float4*)(v + 4) = *(const float4*)(coords + (size_t)c * D + k8 * 8 + 4);
    short8 hi, lo;
    split8(v, &hi, &lo);
    int ch = c >> 6, nl = c & 63;
    size_t off = (size_t)ch * (NCH * 128) + ((size_t)nl * 16 + (k8 ^ (nl & 15))) * 8;
    *(short8*)(Bh + off) = hi;
    *(short8*)(Bl + off) = lo;
    float p = 0.f;
#pragma unroll
    for (int j = 0; j < 8; ++j) p = fmaf(v[j], v[j], p);
#pragma unroll
    for (int m = 1; m <= 8; m <<= 1) p += __shfl_xor(p, m, 64);
    if (k8 == 0) c2[c] = p;
}

// ---------------- main kernel ----------------

__global__ __launch_bounds__(256, 3) void centroid_fast(
        const float* __restrict__ latent,
        const unsigned short* __restrict__ Bh_img,
        const unsigned short* __restrict__ Bl_img,
        const float* __restrict__ c2g,
        int* __restrict__ out,
        int* __restrict__ counter,
        int* __restrict__ worklist) {
    __shared__ __align__(16) unsigned short Bh[NCH * 128], Bl[NCH * 128]; // 32 KB
    __shared__ float sc2[NCH];
    __shared__ float xb1[128], xb2[128];
    __shared__ int   xix[128];

    const int tid  = threadIdx.x;
    const int wid  = tid >> 6;
    const int lane = tid & 63;
    const int wm   = wid >> 1, wn = wid & 1;
    const int q    = lane >> 4, lr = lane & 15;
    const int row_block = blockIdx.x * 128;

    // A fragments: lane holds A[m = lr][k = ks*32 + q*8 .. +8] for rows
    // wm*64 + mt*16 + lr -> 8 consecutive floats, loaded directly, split hi/lo.
    short8 Ah[4][4], Al[4][4];
#pragma unroll
    for (int mt = 0; mt < 4; ++mt) {
        const float* rp = latent + (size_t)(row_block + wm * 64 + mt * 16 + lr) * D;
#pragma unroll
        for (int ks = 0; ks < 4; ++ks) {
            float v[8];
            *(float4*)(v)     = *(const float4*)(rp + ks * 32 + q * 8);
            *(float4*)(v + 4) = *(const float4*)(rp + ks * 32 + q * 8 + 4);
            split8(v, &Ah[mt][ks], &Al[mt][ks]);
        }
    }

    float b1[16], b2[16];
    int   bidx[16];
#pragma unroll
    for (int s = 0; s < 16; ++s) { b1[s] = 3.4e38f; b2[s] = 3.4e38f; bidx[s] = 0; }

    for (int ch = 0; ch < NCHUNKS; ++ch) {
        __syncthreads();   // prior chunk's ds_reads done
        {   // stage 16 KB x2, contiguous
            const unsigned short* sh = Bh_img + (size_t)ch * (NCH * 128);
            const unsigned short* sl = Bl_img + (size_t)ch * (NCH * 128);
#pragma unroll
            for (int i = 0; i < 4; ++i) {
                int e = (i * 256 + tid) * 8;
                *(short8*)(Bh + e) = *(const short8*)(sh + e);
                *(short8*)(Bl + e) = *(const short8*)(sl + e);
            }
            if (tid < NCH) sc2[tid] = c2g[ch * NCH + tid];
        }
        __syncthreads();

#pragma unroll
        for (int nt = 0; nt < 2; ++nt) {
            const int nl = wn * 32 + nt * 16 + lr;
            f32x4 acc[4];
#pragma unroll
            for (int mt = 0; mt < 4; ++mt) acc[mt] = (f32x4){0.f, 0.f, 0.f, 0.f};
#pragma unroll
            for (int ks = 0; ks < 4; ++ks) {
                const int xv = ((ks * 4) | q) ^ lr;     // swizzle: conflict-free
                const int e  = nl * 128 + xv * 8;
                short8 bh = *(const short8*)(Bh + e);
                short8 bl = *(const short8*)(Bl + e);
#pragma unroll
                for (int mt = 0; mt < 4; ++mt) {
                    acc[mt] = __builtin_amdgcn_mfma_f32_16x16x32_bf16(Ah[mt][ks], bh, acc[mt], 0, 0, 0);
                    acc[mt] = __builtin_amdgcn_mfma_f32_16x16x32_bf16(Ah[mt][ks], bl, acc[mt], 0, 0, 0);
                    acc[mt] = __builtin_amdgcn_mfma_f32_16x16x32_bf16(Al[mt][ks], bh, acc[mt], 0, 0, 0);
                }
            }
            const float c2v = sc2[nl];
            const int n_global = ch * NCH + nl;
#pragma unroll
            for (int mt = 0; mt < 4; ++mt)
#pragma unroll
                for (int r = 0; r < 4; ++r) {
                    int slot = mt * 4 + r;
                    float s = fmaf(-2.f, acc[mt][r], c2v);
                    bool lt = s < b1[slot];
                    float t = fmaxf(s, b1[slot]);
                    b2[slot]   = fminf(b2[slot], t);
                    b1[slot]   = fminf(s, b1[slot]);
                    bidx[slot] = lt ? n_global : bidx[slot];
                }
        }
    }

    // butterfly over the 16 col-residue lanes
#pragma unroll
    for (int m = 1; m <= 8; m <<= 1) {
#pragma unroll
        for (int s = 0; s < 16; ++s) {
            float ob1 = __shfl_xor(b1[s], m, 64);
            float ob2 = __shfl_xor(b2[s], m, 64);
            int   oix = __shfl_xor(bidx[s], m, 64);
            float mx  = fmaxf(b1[s], ob1);
            b2[s] = fminf(fminf(b2[s], ob2), mx);
            bool take = (ob1 < b1[s]) || (ob1 == b1[s] && oix < bidx[s]);
            b1[s]   = take ? ob1 : b1[s];
            bidx[s] = take ? oix : bidx[s];
        }
    }
    // merge wn halves via LDS exchange; wn=0 writes
    if (wn == 1) {
#pragma unroll
        for (int s = 0; s < 16; ++s)
            if (lr == s) {
                int rw = wm * 64 + (s >> 2) * 16 + q * 4 + (s & 3);
                xb1[rw] = b1[s]; xb2[rw] = b2[s]; xix[rw] = bidx[s];
            }
    }
    __syncthreads();
    if (wn == 0) {
#pragma unroll
        for (int s = 0; s < 16; ++s)
            if (lr == s) {
                int rw = wm * 64 + (s >> 2) * 16 + q * 4 + (s & 3);
                float ob1 = xb1[rw], ob2 = xb2[rw];
                int   oix = xix[rw];
                float mx  = fmaxf(b1[s], ob1);
                float nb2 = fminf(fminf(b2[s], ob2), mx);
                bool take = (ob1 < b1[s]) || (ob1 == b1[s] && oix < bidx[s]);
                float nb1 = take ? ob1 : b1[s];
                int   nix = take ? oix : bidx[s];
                out[row_block + rw] = nix;
                if (nb2 - nb1 < MARGIN) {
                    int w = atomicAdd(counter, 1);
                    if (w < WL_CAP) worklist[w] = row_block + rw;
                }
            }
    }
}

// ---------------- fp64 refine ----------------

__global__ __launch_bounds__(256) void refine_fp64(
        const float* __restrict__ latent, const float* __restrict__ coords,
        const int* __restrict__ worklist, const int* __restrict__ counter,
        int wl_cap, int* __restrict__ out) {
    __shared__ float  xs[D];
    __shared__ double rv[256];
    __shared__ int    ri[256];

    int n = *counter;
    if (n > wl_cap) n = wl_cap;

    for (int wi = blockIdx.x; wi < n; wi += gridDim.x) {
        int row = worklist[wi];
        if (threadIdx.x < D)
            xs[threadIdx.x] = latent[(size_t)row * D + threadIdx.x];
        __syncthreads();

        double best = 1.0e300;
        int    bix  = 0;
        for (int c = threadIdx.x; c < C; c += 256) {
            const float4* cp = (const float4*)(coords + (size_t)c * D);
            double s = 0.0;
#pragma unroll 8
            for (int k4 = 0; k4 < 32; ++k4) {
                float4 v = cp[k4];
                double d0 = (double)xs[k4 * 4 + 0] - (double)v.x;
                double d1 = (double)xs[k4 * 4 + 1] - (double)v.y;
                double d2 = (double)xs[k4 * 4 + 2] - (double)v.z;
                double d3 = (double)xs[k4 * 4 + 3] - (double)v.w;
                s = fma(d0, d0, s); s = fma(d1, d1, s);
                s = fma(d2, d2, s); s = fma(d3, d3, s);
            }
            if (s < best) { best = s; bix = c; }
        }
        rv[threadIdx.x] = best;
        ri[threadIdx.x] = bix;
        __syncthreads();
        for (int off = 128; off > 0; off >>= 1) {
            if (threadIdx.x < off) {
                double ov = rv[threadIdx.x + off];
                int    oi = ri[threadIdx.x + off];
                if (ov < rv[threadIdx.x] ||
                    (ov == rv[threadIdx.x] && oi < ri[threadIdx.x])) {
                    rv[threadIdx.x] = ov;
                    ri[threadIdx.x] = oi;
                }
            }
            __syncthreads();
        }
        if (threadIdx.x == 0) out[row] = ri[0];
        __syncthreads();
    }
}

extern "C" void kernel_launch(void* const* d_in, const int* in_sizes, int n_in,
                              void* d_out, int out_size, void* d_ws, size_t ws_size,
                              hipStream_t stream) {
    const float* latent = (const float*)d_in[0];
    const float* coords = (const float*)d_in[1];
    int*         out    = (int*)d_out;

    char* ws = (char*)d_ws;
    float* c2      = (float*)ws;
    int*   counter = (int*)(ws + WS_CNT);
    int*   wl      = (int*)(ws + WS_WL);
    unsigned short* Bh = (unsigned short*)(ws + WS_BH);
    unsigned short* Bl = (unsigned short*)(ws + WS_BL);
    const int n_rows = in_sizes[0] / D;   // 131072

    prep_coords<<<(C * 16) / 256, 256, 0, stream>>>(coords, Bh, Bl, c2, counter);
    centroid_fast<<<n_rows / 128, 256, 0, stream>>>(latent, Bh, Bl, c2, out,
                                                    counter, wl);
    refine_fp64<<<608, 256, 0, stream>>>(latent, coords, wl, counter, WL_CAP, out);
}

// Round 7
// 327.304 us; speedup vs baseline: 5.0396x; 5.0396x over previous
//
#include <hip/hip_runtime.h>

// Centroids: argmin_c ||latent[r] - coords[c]||^2, 131072 rows x 2048 coords, D=128.
//
// prep_coords: coords -> bf16 hi/lo "B images", XOR-swizzled granules (contiguous
//   LDS copy AND conflict-free frag ds_read_b128), + c2, + counter=0.
// centroid_fast: each wave owns 32 rows x ALL cols (R6 lesson: 64-row waves need
//   128 VGPRs of A frags; launch_bounds(256,3)'s ~168-total cap spilled them to
//   scratch -> 5.3 GB HBM traffic. 32-row waves: A frags = 64 VGPRs, no wn-merge).
//   A fragments f32->bf16x2 in-register from latent (frag = 8 consecutive floats
//   per lane). Per 64-coord chunk: stage 32 KB B, 32 ds_read_b128/wave, bf16x2
//   3-pass MFMA (Ahh+Ahl+Alh), fused argmin epilogue, 16-lane butterfly.
// refine_fp64: rows with gap < MARGIN recomputed exactly in fp64 (~0.5%).
//
// ws layout (bytes): 0 c2 | 8192 counter | 16384 worklist(128KB) |
//                    262144 Bh (512KB) | 786432 Bl (512KB) | end 1310720

constexpr int D = 128;
constexpr int C = 2048;
constexpr int NCH = 64;            // coords per chunk
constexpr int NCHUNKS = C / NCH;   // 32
constexpr float MARGIN = 0.02f;    // bf16x2 worst-case score err ~5e-3 -> 4x headroom
constexpr int WL_CAP = 32768;

constexpr size_t WS_CNT = 8192;
constexpr size_t WS_WL  = 16384;
constexpr size_t WS_BH  = 262144;
constexpr size_t WS_BL  = 786432;

typedef __attribute__((ext_vector_type(8))) short short8;
typedef __attribute__((ext_vector_type(4))) float f32x4;

__device__ inline unsigned short bf16_rne(float x) {
    unsigned u = __float_as_uint(x);
    u += 0x7FFFu + ((u >> 16) & 1u);
    return (unsigned short)(u >> 16);
}
__device__ inline float bf16_to_f(unsigned short h) {
    return __uint_as_float(((unsigned)h) << 16);
}
__device__ inline void split8(const float* v, short8* hi, short8* lo) {
#pragma unroll
    for (int j = 0; j < 8; ++j) {
        unsigned short h = bf16_rne(v[j]);
        (*hi)[j] = (short)h;
        (*lo)[j] = (short)bf16_rne(v[j] - bf16_to_f(h));
    }
}

// ---------------- prep: B images + c2 ----------------
// 32768 threads: thread t -> coord c = t>>4, k-granule k8 = t&15.
// Image: chunk ch = c>>6, nl = c&63; granule g = nl*16 + (k8 ^ (nl&15)).
__global__ void prep_coords(const float* __restrict__ coords,
                            unsigned short* __restrict__ Bh,
                            unsigned short* __restrict__ Bl,
                            float* __restrict__ c2, int* __restrict__ counter) {
    int t = blockIdx.x * blockDim.x + threadIdx.x;
    if (t == 0) *counter = 0;
    if (t >= C * 16) return;
    int c  = t >> 4;
    int k8 = t & 15;
    float v[8];
    *(float4*)(v)     = *(const float4*)(coords + (size_t)c * D + k8 * 8);
    *(float4*)(v + 4) = *(const float4*)(coords + (size_t)c * D + k8 * 8 + 4);
    short8 hi, lo;
    split8(v, &hi, &lo);
    int ch = c >> 6, nl = c & 63;
    size_t off = (size_t)ch * (NCH * 128) + ((size_t)nl * 16 + (k8 ^ (nl & 15))) * 8;
    *(short8*)(Bh + off) = hi;
    *(short8*)(Bl + off) = lo;
    float p = 0.f;
#pragma unroll
    for (int j = 0; j < 8; ++j) p = fmaf(v[j], v[j], p);
#pragma unroll
    for (int m = 1; m <= 8; m <<= 1) p += __shfl_xor(p, m, 64);
    if (k8 == 0) c2[c] = p;
}

// ---------------- main kernel ----------------

__global__ __launch_bounds__(256, 3) void centroid_fast(
        const float* __restrict__ latent,
        const unsigned short* __restrict__ Bh_img,
        const unsigned short* __restrict__ Bl_img,
        const float* __restrict__ c2g,
        int* __restrict__ out,
        int* __restrict__ counter,
        int* __restrict__ worklist) {
    __shared__ __align__(16) unsigned short Bh[NCH * 128], Bl[NCH * 128]; // 32 KB
    __shared__ float sc2[NCH];

    const int tid  = threadIdx.x;
    const int wid  = tid >> 6;            // wave 0..3 -> rows wid*32..wid*32+31
    const int lane = tid & 63;
    const int q    = lane >> 4, lr = lane & 15;
    const int row_block = blockIdx.x * 128;

    // A fragments: lane holds A[m = lr][k = ks*32 + q*8 .. +8] for rows
    // wid*32 + mt*16 + lr -> 8 consecutive floats, loaded directly, split hi/lo.
    // 16 short8 = 64 VGPRs long-lived.
    short8 Ah[2][4], Al[2][4];
#pragma unroll
    for (int mt = 0; mt < 2; ++mt) {
        const float* rp = latent + (size_t)(row_block + wid * 32 + mt * 16 + lr) * D;
#pragma unroll
        for (int ks = 0; ks < 4; ++ks) {
            float v[8];
            *(float4*)(v)     = *(const float4*)(rp + ks * 32 + q * 8);
            *(float4*)(v + 4) = *(const float4*)(rp + ks * 32 + q * 8 + 4);
            split8(v, &Ah[mt][ks], &Al[mt][ks]);
        }
    }

    float b1[8], b2[8];
    int   bidx[8];
#pragma unroll
    for (int s = 0; s < 8; ++s) { b1[s] = 3.4e38f; b2[s] = 3.4e38f; bidx[s] = 0; }

    for (int ch = 0; ch < NCHUNKS; ++ch) {
        __syncthreads();   // prior chunk's ds_reads done
        {   // stage 16 KB x2, contiguous
            const unsigned short* sh = Bh_img + (size_t)ch * (NCH * 128);
            const unsigned short* sl = Bl_img + (size_t)ch * (NCH * 128);
#pragma unroll
            for (int i = 0; i < 4; ++i) {
                int e = (i * 256 + tid) * 8;
                *(short8*)(Bh + e) = *(const short8*)(sh + e);
                *(short8*)(Bl + e) = *(const short8*)(sl + e);
            }
            if (tid < NCH) sc2[tid] = c2g[ch * NCH + tid];
        }
        __syncthreads();

#pragma unroll
        for (int nt = 0; nt < 4; ++nt) {
            const int nl = nt * 16 + lr;
            f32x4 acc[2];
#pragma unroll
            for (int mt = 0; mt < 2; ++mt) acc[mt] = (f32x4){0.f, 0.f, 0.f, 0.f};
#pragma unroll
            for (int ks = 0; ks < 4; ++ks) {
                const int xv = ((ks * 4) | q) ^ lr;     // swizzle: conflict-free
                const int e  = nl * 128 + xv * 8;
                short8 bh = *(const short8*)(Bh + e);
                short8 bl = *(const short8*)(Bl + e);
#pragma unroll
                for (int mt = 0; mt < 2; ++mt) {
                    acc[mt] = __builtin_amdgcn_mfma_f32_16x16x32_bf16(Ah[mt][ks], bh, acc[mt], 0, 0, 0);
                    acc[mt] = __builtin_amdgcn_mfma_f32_16x16x32_bf16(Ah[mt][ks], bl, acc[mt], 0, 0, 0);
                    acc[mt] = __builtin_amdgcn_mfma_f32_16x16x32_bf16(Al[mt][ks], bh, acc[mt], 0, 0, 0);
                }
            }
            const float c2v = sc2[nl];
            const int n_global = ch * NCH + nl;
#pragma unroll
            for (int mt = 0; mt < 2; ++mt)
#pragma unroll
                for (int r = 0; r < 4; ++r) {
                    int slot = mt * 4 + r;
                    float s = fmaf(-2.f, acc[mt][r], c2v);
                    bool lt = s < b1[slot];
                    float t = fmaxf(s, b1[slot]);
                    b2[slot]   = fminf(b2[slot], t);
                    b1[slot]   = fminf(s, b1[slot]);
                    bidx[slot] = lt ? n_global : bidx[slot];
                }
        }
    }

    // butterfly over the 16 col-residue lanes (cols live in lr within each quad)
#pragma unroll
    for (int m = 1; m <= 8; m <<= 1) {
#pragma unroll
        for (int s = 0; s < 8; ++s) {
            float ob1 = __shfl_xor(b1[s], m, 64);
            float ob2 = __shfl_xor(b2[s], m, 64);
            int   oix = __shfl_xor(bidx[s], m, 64);
            float mx  = fmaxf(b1[s], ob1);
            b2[s] = fminf(fminf(b2[s], ob2), mx);
            bool take = (ob1 < b1[s]) || (ob1 == b1[s] && oix < bidx[s]);
            b1[s]   = take ? ob1 : b1[s];
            bidx[s] = take ? oix : bidx[s];
        }
    }
    // slot s canonical in lane lr==s; row = wid*32 + (s>>2)*16 + q*4 + (s&3)
#pragma unroll
    for (int s = 0; s < 8; ++s) {
        if (lr == s) {
            int row = row_block + wid * 32 + (s >> 2) * 16 + q * 4 + (s & 3);
            out[row] = bidx[s];
            if (b2[s] - b1[s] < MARGIN) {
                int w = atomicAdd(counter, 1);
                if (w < WL_CAP) worklist[w] = row;
            }
        }
    }
}

// ---------------- fp64 refine ----------------

__global__ __launch_bounds__(256) void refine_fp64(
        const float* __restrict__ latent, const float* __restrict__ coords,
        const int* __restrict__ worklist, const int* __restrict__ counter,
        int wl_cap, int* __restrict__ out) {
    __shared__ float  xs[D];
    __shared__ double rv[256];
    __shared__ int    ri[256];

    int n = *counter;
    if (n > wl_cap) n = wl_cap;

    for (int wi = blockIdx.x; wi < n; wi += gridDim.x) {
        int row = worklist[wi];
        if (threadIdx.x < D)
            xs[threadIdx.x] = latent[(size_t)row * D + threadIdx.x];
        __syncthreads();

        double best = 1.0e300;
        int    bix  = 0;
        for (int c = threadIdx.x; c < C; c += 256) {
            const float4* cp = (const float4*)(coords + (size_t)c * D);
            double s = 0.0;
#pragma unroll 8
            for (int k4 = 0; k4 < 32; ++k4) {
                float4 v = cp[k4];
                double d0 = (double)xs[k4 * 4 + 0] - (double)v.x;
                double d1 = (double)xs[k4 * 4 + 1] - (double)v.y;
                double d2 = (double)xs[k4 * 4 + 2] - (double)v.z;
                double d3 = (double)xs[k4 * 4 + 3] - (double)v.w;
                s = fma(d0, d0, s); s = fma(d1, d1, s);
                s = fma(d2, d2, s); s = fma(d3, d3, s);
            }
            if (s < best) { best = s; bix = c; }
        }
        rv[threadIdx.x] = best;
        ri[threadIdx.x] = bix;
        __syncthreads();
        for (int off = 128; off > 0; off >>= 1) {
            if (threadIdx.x < off) {
                double ov = rv[threadIdx.x + off];
                int    oi = ri[threadIdx.x + off];
                if (ov < rv[threadIdx.x] ||
                    (ov == rv[threadIdx.x] && oi < ri[threadIdx.x])) {
                    rv[threadIdx.x] = ov;
                    ri[threadIdx.x] = oi;
                }
            }
            __syncthreads();
        }
        if (threadIdx.x == 0) out[row] = ri[0];
        __syncthreads();
    }
}

extern "C" void kernel_launch(void* const* d_in, const int* in_sizes, int n_in,
                              void* d_out, int out_size, void* d_ws, size_t ws_size,
                              hipStream_t stream) {
    const float* latent = (const float*)d_in[0];
    const float* coords = (const float*)d_in[1];
    int*         out    = (int*)d_out;

    char* ws = (char*)d_ws;
    float* c2      = (float*)ws;
    int*   counter = (int*)(ws + WS_CNT);
    int*   wl      = (int*)(ws + WS_WL);
    unsigned short* Bh = (unsigned short*)(ws + WS_BH);
    unsigned short* Bl = (unsigned short*)(ws + WS_BL);
    const int n_rows = in_sizes[0] / D;   // 131072

    prep_coords<<<(C * 16) / 256, 256, 0, stream>>>(coords, Bh, Bl, c2, counter);
    centroid_fast<<<n_rows / 128, 256, 0, stream>>>(latent, Bh, Bl, c2, out,
                                                    counter, wl);
    refine_fp64<<<608, 256, 0, stream>>>(latent, coords, wl, counter, WL_CAP, out);
}